// Round 6
// baseline (54.154 us; speedup 1.0000x reference)
//
#include <hip/hip_runtime.h>
#include <hip/hip_bf16.h>
#include <math.h>

#define N_DIM 4096
#define H_DIM 256
#define C_DIM 151
#define KP    448   // 256 + 192 (151 real + 41 zero); 7 K-steps of 64
#define KT    160   // tail GEMM K: 151 padded to 160 (5 steps of 32)

typedef unsigned short ushort_t;
typedef __attribute__((ext_vector_type(8))) short bf16x8;
typedef __attribute__((ext_vector_type(4))) float f32x4;

// ---------------- workspace layout (BYTE offsets) ----------------
#define WSB_PPACK  0          // bf16[4096*256]
#define WSB_WT     2097152    // bf16[2][256*256]
#define WSB_DPACK  2359296    // bf16[4096*160]
#define WSB_COT    3670016    // bf16[192*160]   co^T, zero-padded
#define WSB_PART   3731456    // f32[16][4096]   bias-dot partials
#define WSB_SPART  3993600    // f32[6][4096]    s row-sum partials
#define WSB_APACK  4091904    // bf16[4096*448]  (obj*w_mul | w_ps*D | 0)
#define WSB_BPACK  7761920    // bf16[4096*448]  (sub       | D@co   | 0)

#define GLL(src, dst) __builtin_amdgcn_global_load_lds( \
    (const __attribute__((address_space(1))) void*)(src), \
    (__attribute__((address_space(3))) void*)(dst), 16, 0, 0)

// Fused converts:
//  [0,512)   P fp32->bf16
//  [512,544) W transpose -> Wt bf16
//  [544,608) D -> Dpack bf16 (pad 160) + Apack tail = bf16(w_ps*D) (pad 192)
//  [608,617) co -> coT bf16 (192x160, zero-padded)
__global__ __launch_bounds__(256) void k_cvt(
    const float* __restrict__ P, const float* __restrict__ Ws,
    const float* __restrict__ Wo, const float* __restrict__ D,
    const float* __restrict__ co, const float* __restrict__ wsc,
    __hip_bfloat16* __restrict__ Pp, __hip_bfloat16* __restrict__ Wt,
    __hip_bfloat16* __restrict__ Dpack, __hip_bfloat16* __restrict__ coT,
    __hip_bfloat16* __restrict__ Apack) {
    __shared__ float shbuf[64 * C_DIM];   // 38.7 KB
    const int t = threadIdx.x;
    const int bid = blockIdx.x;
    if (bid < 512) {
        int idx = (bid * 256 + t) * 8;
        float4 a = *(const float4*)(P + idx);
        float4 b = *(const float4*)(P + idx + 4);
        __hip_bfloat16 h[8];
        h[0] = __float2bfloat16(a.x); h[1] = __float2bfloat16(a.y);
        h[2] = __float2bfloat16(a.z); h[3] = __float2bfloat16(a.w);
        h[4] = __float2bfloat16(b.x); h[5] = __float2bfloat16(b.y);
        h[6] = __float2bfloat16(b.z); h[7] = __float2bfloat16(b.w);
        *(bf16x8*)&Pp[idx] = *(bf16x8*)h;
    } else if (bid < 544) {
        const int b  = bid - 512;
        const int k0 = (b & 3) * 64;
        const int h0 = ((b >> 2) & 3) * 64;
        const int z  = b >> 4;
        const float* W = z ? Wo : Ws;
        #pragma unroll
        for (int q = 0; q < 4; ++q) {
            int r = (t >> 4) + q * 16;
            int c = (t & 15) * 4;
            float4 f = *(const float4*)&W[(size_t)(k0 + r) * H_DIM + h0 + c];
            shbuf[r * 65 + c] = f.x; shbuf[r * 65 + c + 1] = f.y;
            shbuf[r * 65 + c + 2] = f.z; shbuf[r * 65 + c + 3] = f.w;
        }
        __syncthreads();
        #pragma unroll
        for (int q = 0; q < 2; ++q) {
            int idx = t + q * 256;
            int h   = idx >> 3;
            int kc  = idx & 7;
            __hip_bfloat16 u[8];
            #pragma unroll
            for (int j = 0; j < 8; ++j)
                u[j] = __float2bfloat16(shbuf[(kc * 8 + j) * 65 + h]);
            *(bf16x8*)&Wt[((size_t)z * H_DIM + h0 + h) * H_DIM + k0 + kc * 8] = *(bf16x8*)u;
        }
    } else if (bid < 608) {
        const int b  = bid - 544;
        const int i0 = b * 64;
        for (int idx = t; idx < 64 * C_DIM; idx += 256)
            shbuf[idx] = D[(size_t)i0 * C_DIM + idx];
        __syncthreads();
        const float wps = wsc[768];
        for (int o = t; o < 64 * (KT / 8); o += 256) {
            int r = o / (KT / 8), ch = o % (KT / 8);
            __hip_bfloat16 u[8];
            #pragma unroll
            for (int j = 0; j < 8; ++j) {
                int k = ch * 8 + j;
                u[j] = __float2bfloat16(k < C_DIM ? shbuf[r * C_DIM + k] : 0.f);
            }
            *(bf16x8*)&Dpack[(size_t)(i0 + r) * KT + ch * 8] = *(bf16x8*)u;
        }
        for (int o = t; o < 64 * 24; o += 256) {
            int r = o / 24, ch = o % 24;
            __hip_bfloat16 u[8];
            #pragma unroll
            for (int j = 0; j < 8; ++j) {
                int c = ch * 8 + j;
                u[j] = __float2bfloat16(c < C_DIM ? wps * shbuf[r * C_DIM + c] : 0.f);
            }
            *(bf16x8*)&Apack[(size_t)(i0 + r) * KP + H_DIM + ch * 8] = *(bf16x8*)u;
        }
    } else {
        const int q  = bid - 608;
        const int a0 = (q % 3) * 64;
        const int c0 = (q / 3) * 64;
        for (int o = t; o < 64 * 64; o += 256) {
            int r = o >> 6, c = o & 63;
            float v = 0.f;
            if (a0 + r < C_DIM && c0 + c < C_DIM)
                v = co[(size_t)(a0 + r) * C_DIM + c0 + c];
            shbuf[r * 65 + c] = v;
        }
        __syncthreads();
        const int nch = (a0 == 128) ? 4 : 8;
        for (int o = t; o < 64 * 8; o += 256) {
            int cl = o >> 3, ch = o & 7;
            if (ch < nch) {
                __hip_bfloat16 u[8];
                #pragma unroll
                for (int j = 0; j < 8; ++j)
                    u[j] = __float2bfloat16(shbuf[(ch * 8 + j) * 65 + cl]);
                *(bf16x8*)&coT[(size_t)(c0 + cl) * KT + a0 + ch * 8] = *(bf16x8*)u;
            }
        }
    }
}

// Merged producer kernel:
//  bid < 256 : sub/obj MFMA (tile 128x64, 4 waves, full-K single stage)
//  bid >= 256: tail MFMA  M = D @ co (64x64 tiles, frags direct from global)
__global__ __launch_bounds__(256) void k_mid(
    const ushort_t* __restrict__ Pp, const ushort_t* __restrict__ Wt,
    const ushort_t* __restrict__ Dpack, const ushort_t* __restrict__ coT,
    const float* __restrict__ bsub, const float* __restrict__ bobj,
    const float* __restrict__ wsc,
    __hip_bfloat16* __restrict__ Apack, __hip_bfloat16* __restrict__ Bpack,
    float* __restrict__ part, float* __restrict__ spart) {
    __shared__ ushort_t As[128 * 256];  // 64 KB
    __shared__ ushort_t Bs[64 * 256];   // 32 KB

    const int t = threadIdx.x;
    const int w = t >> 6, l = t & 63;
    const int wr = w >> 1, wc = w & 1;
    const int lr = l & 15, g = l >> 4;
    const int bid = blockIdx.x;

    if (bid < 256) {
        const int hblk = bid & 3;
        const int i0   = ((bid >> 2) & 31) * 128;
        const int z    = bid >> 7;
        const int j0   = hblk * 64;
        const float* bias = z ? bobj : bsub;
        const ushort_t* Wz = Wt + (size_t)z * H_DIM * H_DIM;

        #pragma unroll
        for (int r_ = 0; r_ < 16; ++r_) {
            int idx = t + r_ * 256, row = idx >> 5, cl = idx & 31;
            int cs = cl ^ (row & 7);
            GLL(Pp + (size_t)(i0 + row) * H_DIM + cs * 8, &As[idx * 8]);
        }
        #pragma unroll
        for (int r_ = 0; r_ < 8; ++r_) {
            int idx = t + r_ * 256, row = idx >> 5, cl = idx & 31;
            int cs = cl ^ (row & 7);
            GLL(Wz + (size_t)(j0 + row) * H_DIM + cs * 8, &Bs[idx * 8]);
        }
        __syncthreads();

        f32x4 acc[4][2];
        #pragma unroll
        for (int m = 0; m < 4; ++m)
            #pragma unroll
            for (int n = 0; n < 2; ++n) acc[m][n] = f32x4{0.f, 0.f, 0.f, 0.f};

        #pragma unroll
        for (int ks2 = 0; ks2 < 8; ++ks2) {
            bf16x8 a[4], b[2];
            int c = ks2 * 4 + g;
            #pragma unroll
            for (int m = 0; m < 4; ++m) {
                int Rl = wr * 64 + m * 16 + lr;
                int cl = c ^ (Rl & 7);
                a[m] = *(const bf16x8*)&As[(Rl * 32 + cl) * 8];
            }
            #pragma unroll
            for (int n = 0; n < 2; ++n) {
                int Rl = wc * 32 + n * 16 + lr;
                int cl = c ^ (Rl & 7);
                b[n] = *(const bf16x8*)&Bs[(Rl * 32 + cl) * 8];
            }
            #pragma unroll
            for (int m = 0; m < 4; ++m)
                #pragma unroll
                for (int n = 0; n < 2; ++n)
                    acc[m][n] = __builtin_amdgcn_mfma_f32_16x16x32_bf16(
                        a[m], b[n], acc[m][n], 0, 0, 0);
        }

        int hn[2]; float bb[2], wse[2], wmu[2];
        #pragma unroll
        for (int n = 0; n < 2; ++n) {
            hn[n]  = j0 + wc * 32 + n * 16 + lr;
            bb[n]  = bias[hn[n]];
            wse[n] = wsc[(z ? 512 : 256) + hn[n]];
            wmu[n] = wsc[hn[n]];
        }
        float* partq = part + (size_t)(z * 8 + hblk * 2 + wc) * N_DIM;
        #pragma unroll
        for (int m = 0; m < 4; ++m) {
            float p[4] = {0.f, 0.f, 0.f, 0.f};
            #pragma unroll
            for (int n = 0; n < 2; ++n)
                #pragma unroll
                for (int r = 0; r < 4; ++r) {
                    float v = acc[m][n][r] + bb[n];
                    v = v > 0.f ? v : 0.f;
                    int i = i0 + wr * 64 + m * 16 + g * 4 + r;
                    if (z) Apack[(size_t)i * KP + hn[n]] = __float2bfloat16(v * wmu[n]);
                    else   Bpack[(size_t)i * KP + hn[n]] = __float2bfloat16(v);
                    p[r] += v * wse[n];
                }
            #pragma unroll
            for (int r = 0; r < 4; ++r) {
                p[r] += __shfl_xor(p[r], 1);
                p[r] += __shfl_xor(p[r], 2);
                p[r] += __shfl_xor(p[r], 4);
                p[r] += __shfl_xor(p[r], 8);
            }
            if (lr == 0)
                #pragma unroll
                for (int r = 0; r < 4; ++r)
                    partq[i0 + wr * 64 + m * 16 + g * 4 + r] = p[r];
        }
    } else {
        const int q  = bid - 256;
        const int j0 = (q % 3) * 64;
        const int i0 = (q / 3) * 64;

        bf16x8 a[2][5], b[2][5];
        #pragma unroll
        for (int m = 0; m < 2; ++m) {
            const ushort_t* ap = Dpack + (size_t)(i0 + wr * 32 + m * 16 + lr) * KT + g * 8;
            #pragma unroll
            for (int ks = 0; ks < 5; ++ks) a[m][ks] = *(const bf16x8*)(ap + ks * 32);
        }
        #pragma unroll
        for (int n = 0; n < 2; ++n) {
            const ushort_t* bp = coT + (size_t)(j0 + wc * 32 + n * 16 + lr) * KT + g * 8;
            #pragma unroll
            for (int ks = 0; ks < 5; ++ks) b[n][ks] = *(const bf16x8*)(bp + ks * 32);
        }

        f32x4 acc[2][2];
        #pragma unroll
        for (int m = 0; m < 2; ++m)
            #pragma unroll
            for (int n = 0; n < 2; ++n) acc[m][n] = f32x4{0.f, 0.f, 0.f, 0.f};
        #pragma unroll
        for (int ks = 0; ks < 5; ++ks)
            #pragma unroll
            for (int m = 0; m < 2; ++m)
                #pragma unroll
                for (int n = 0; n < 2; ++n)
                    acc[m][n] = __builtin_amdgcn_mfma_f32_16x16x32_bf16(
                        a[m][ks], b[n][ks], acc[m][n], 0, 0, 0);

        float* sp = spart + (size_t)((q % 3) * 2 + wc) * N_DIM;
        #pragma unroll
        for (int m = 0; m < 2; ++m) {
            float p[4] = {0.f, 0.f, 0.f, 0.f};
            #pragma unroll
            for (int n = 0; n < 2; ++n) {
                int col = j0 + wc * 32 + n * 16 + lr;
                #pragma unroll
                for (int r = 0; r < 4; ++r) {
                    int i = i0 + wr * 32 + m * 16 + g * 4 + r;
                    float v = acc[m][n][r];
                    Bpack[(size_t)i * KP + H_DIM + col] = __float2bfloat16(v);
                    p[r] += v;
                }
            }
            #pragma unroll
            for (int r = 0; r < 4; ++r) {
                p[r] += __shfl_xor(p[r], 1);
                p[r] += __shfl_xor(p[r], 2);
                p[r] += __shfl_xor(p[r], 4);
                p[r] += __shfl_xor(p[r], 8);
            }
            if (lr == 0)
                #pragma unroll
                for (int r = 0; r < 4; ++r)
                    sp[i0 + wr * 32 + m * 16 + g * 4 + r] = p[r];
        }
    }
}

// Main: 256x128 tiles, 512 blocks (2 generations/CU -> write/compute overlap).
// 8 waves (4M x 2N), wave-tile 64x64, BK=64, 2-phase dbuf, LDS-bounce epilogue.
__global__ __launch_bounds__(512) void k_main(
    const ushort_t* __restrict__ Apack, const ushort_t* __restrict__ Bpack,
    const float* __restrict__ part, const float* __restrict__ spart,
    const float* __restrict__ wsc, const float* __restrict__ bsc,
    float* __restrict__ out) {
    __shared__ ushort_t pa[2][256 * 64];   // 64 KB
    __shared__ ushort_t pb[2][128 * 64];   // 32 KB
    __shared__ float rbS[256], cbS[128];

    const int t = threadIdx.x;
    const int w = t >> 6, l = t & 63;
    const int wm = w >> 1, wn = w & 1;
    const int lr = l & 15, g = l >> 4;
    const int bid = blockIdx.x;
    const int wgid = (bid & 7) * 64 + (bid >> 3);   // XCD swizzle, 512 % 8 == 0
    const int i0 = (wgid >> 5) * 256;
    const int j0 = (wgid & 31) * 128;

#define K_STAGE(buf, ks) do {                                                   \
    _Pragma("unroll")                                                           \
    for (int r_ = 0; r_ < 4; ++r_) {                                            \
        int idx_ = t + r_ * 512, row_ = idx_ >> 3, cl_ = idx_ & 7;              \
        int cs_ = cl_ ^ (row_ & 7);                                             \
        GLL(Apack + (size_t)(i0+row_)*KP + (ks)*64 + cs_*8, &pa[buf][idx_*8]);  \
    }                                                                           \
    _Pragma("unroll")                                                           \
    for (int r_ = 0; r_ < 2; ++r_) {                                            \
        int idx_ = t + r_ * 512, row_ = idx_ >> 3, cl_ = idx_ & 7;              \
        int cs_ = cl_ ^ (row_ & 7);                                             \
        GLL(Bpack + (size_t)(j0+row_)*KP + (ks)*64 + cs_*8, &pb[buf][idx_*8]);  \
    }                                                                           \
} while (0)

    K_STAGE(0, 0);
    // fused bias computation (overlaps stage-0 latency)
    if (t < 256) {
        int i = i0 + t; float r = 0.f, si = 0.f;
        #pragma unroll
        for (int q = 8; q < 16; ++q) r += part[(size_t)q * N_DIM + i];
        #pragma unroll
        for (int q = 0; q < 6; ++q) si += spart[(size_t)q * N_DIM + i];
        rbS[t] = r + wsc[770] * si;
    } else if (t < 384) {
        int j = j0 + (t - 256); float c = 0.f, sj = 0.f;
        #pragma unroll
        for (int q = 0; q < 8; ++q) c += part[(size_t)q * N_DIM + j];
        #pragma unroll
        for (int q = 0; q < 6; ++q) sj += spart[(size_t)q * N_DIM + j];
        cbS[t - 256] = c + wsc[769] * sj + bsc[0];
    }
    __syncthreads();

    f32x4 acc[4][4];
    #pragma unroll
    for (int m = 0; m < 4; ++m)
        #pragma unroll
        for (int n = 0; n < 4; ++n) acc[m][n] = f32x4{0.f, 0.f, 0.f, 0.f};

    for (int ks = 0; ks < 7; ++ks) {
        const int cur = ks & 1;
        if (ks < 6) K_STAGE(cur ^ 1, ks + 1);
        #pragma unroll
        for (int ks2 = 0; ks2 < 2; ++ks2) {
            bf16x8 a[4], b[4];
            int c = ks2 * 4 + g;
            #pragma unroll
            for (int m = 0; m < 4; ++m) {
                int Rl = wm * 64 + m * 16 + lr;
                int cl = c ^ (Rl & 7);
                a[m] = *(const bf16x8*)&pa[cur][(Rl * 8 + cl) * 8];
            }
            #pragma unroll
            for (int n = 0; n < 4; ++n) {
                int Rl = wn * 64 + n * 16 + lr;
                int cl = c ^ (Rl & 7);
                b[n] = *(const bf16x8*)&pb[cur][(Rl * 8 + cl) * 8];
            }
            #pragma unroll
            for (int m = 0; m < 4; ++m)
                #pragma unroll
                for (int n = 0; n < 4; ++n)
                    acc[m][n] = __builtin_amdgcn_mfma_f32_16x16x32_bf16(
                        a[m], b[n], acc[m][n], 0, 0, 0);
        }
        __syncthreads();
    }
#undef K_STAGE

    // Epilogue: sigmoid -> LDS bounce (64 rows x 128 cols per m) -> float4 stores
    float cbv[4];
    #pragma unroll
    for (int n = 0; n < 4; ++n) cbv[n] = cbS[wn * 64 + n * 16 + lr];
    float* OutS = (float*)pa;   // [64][132] f32 = 33.8 KB <= 64 KB
    #pragma unroll
    for (int m = 0; m < 4; ++m) {
        #pragma unroll
        for (int n = 0; n < 4; ++n) {
            #pragma unroll
            for (int r = 0; r < 4; ++r) {
                float rb = rbS[wm * 64 + m * 16 + g * 4 + r];
                float v  = acc[m][n][r] + rb + cbv[n];
                float e  = __expf(-v);
                OutS[(wm * 16 + g * 4 + r) * 132 + wn * 64 + n * 16 + lr] =
                    __builtin_amdgcn_rcpf(1.0f + e);
            }
        }
        __syncthreads();
        {
            int rl = t >> 3, c8 = t & 7;
            int gr = i0 + (rl >> 4) * 64 + m * 16 + (rl & 15);
            float* op = out + (size_t)gr * N_DIM + j0;
            const float* rp = OutS + rl * 132;
            #pragma unroll
            for (int k = 0; k < 4; ++k) {
                float4 v4 = *(const float4*)(rp + (c8 + 8 * k) * 4);
                *(float4*)(op + (c8 + 8 * k) * 4) = v4;
            }
        }
        __syncthreads();
    }
}

extern "C" void kernel_launch(void* const* d_in, const int* in_sizes, int n_in,
                              void* d_out, int out_size, void* d_ws, size_t ws_size,
                              hipStream_t stream) {
    const float* prepro = (const float*)d_in[0];
    const float* D      = (const float*)d_in[1];
    const float* co     = (const float*)d_in[2];
    const float* Wsub   = (const float*)d_in[3];
    const float* bsub   = (const float*)d_in[4];
    const float* Wobj   = (const float*)d_in[5];
    const float* bobj   = (const float*)d_in[6];
    const float* wsc    = (const float*)d_in[7];
    const float* bsc    = (const float*)d_in[8];
    float* out = (float*)d_out;

    char* ws = (char*)d_ws;
    __hip_bfloat16* Ppack = (__hip_bfloat16*)(ws + WSB_PPACK);
    __hip_bfloat16* Wt    = (__hip_bfloat16*)(ws + WSB_WT);
    __hip_bfloat16* Dpack = (__hip_bfloat16*)(ws + WSB_DPACK);
    __hip_bfloat16* coT   = (__hip_bfloat16*)(ws + WSB_COT);
    float* part  = (float*)(ws + WSB_PART);
    float* spart = (float*)(ws + WSB_SPART);
    __hip_bfloat16* Apack = (__hip_bfloat16*)(ws + WSB_APACK);
    __hip_bfloat16* Bpack = (__hip_bfloat16*)(ws + WSB_BPACK);

    k_cvt<<<617, 256, 0, stream>>>(prepro, Wsub, Wobj, D, co, wsc,
                                   Ppack, Wt, Dpack, coT, Apack);
    k_mid<<<448, 256, 0, stream>>>(
        (const ushort_t*)Ppack, (const ushort_t*)Wt,
        (const ushort_t*)Dpack, (const ushort_t*)coT,
        bsub, bobj, wsc, Apack, Bpack, part, spart);
    k_main<<<512, 512, 0, stream>>>(
        (const ushort_t*)Apack, (const ushort_t*)Bpack, part, spart, wsc, bsc, out);
}

// Round 7
// 49.219 us; speedup vs baseline: 1.1003x; 1.1003x over previous
//
#include <hip/hip_runtime.h>
#include <hip/hip_bf16.h>
#include <math.h>

#define N_DIM 4096
#define H_DIM 256
#define C_DIM 151
#define KP    448   // 256 + 192 (151 real + 41 zero); 7 K-steps of 64
#define KT    160   // tail GEMM K: 151 padded to 160 (5 steps of 32)

typedef unsigned short ushort_t;
typedef __attribute__((ext_vector_type(8))) short bf16x8;
typedef __attribute__((ext_vector_type(4))) float f32x4;

// ---------------- workspace layout (BYTE offsets) ----------------
#define WSB_PPACK  0          // bf16[4096*256]
#define WSB_WT     2097152    // bf16[2][256*256]
#define WSB_DPACK  2359296    // bf16[4096*160]
#define WSB_COT    3670016    // bf16[192*160]   co^T, zero-padded
#define WSB_PART   3731456    // f32[16][4096]   bias-dot partials
#define WSB_SPART  3993600    // f32[6][4096]    s row-sum partials
#define WSB_APACK  4091904    // bf16[4096*448]  (obj*w_mul | w_ps*D | 0)
#define WSB_BPACK  7761920    // bf16[4096*448]  (sub       | D@co   | 0)

#define GLL(src, dst) __builtin_amdgcn_global_load_lds( \
    (const __attribute__((address_space(1))) void*)(src), \
    (__attribute__((address_space(3))) void*)(dst), 16, 0, 0)

// Fused converts:
//  [0,512)   P fp32->bf16
//  [512,544) W transpose -> Wt bf16
//  [544,608) D -> Dpack bf16 (pad 160) + Apack tail = bf16(w_ps*D) (pad 192)
//  [608,617) co -> coT bf16 (192x160, zero-padded)
__global__ __launch_bounds__(256) void k_cvt(
    const float* __restrict__ P, const float* __restrict__ Ws,
    const float* __restrict__ Wo, const float* __restrict__ D,
    const float* __restrict__ co, const float* __restrict__ wsc,
    __hip_bfloat16* __restrict__ Pp, __hip_bfloat16* __restrict__ Wt,
    __hip_bfloat16* __restrict__ Dpack, __hip_bfloat16* __restrict__ coT,
    __hip_bfloat16* __restrict__ Apack) {
    __shared__ float shbuf[64 * C_DIM];   // 38.7 KB
    const int t = threadIdx.x;
    const int bid = blockIdx.x;
    if (bid < 512) {
        int idx = (bid * 256 + t) * 8;
        float4 a = *(const float4*)(P + idx);
        float4 b = *(const float4*)(P + idx + 4);
        __hip_bfloat16 h[8];
        h[0] = __float2bfloat16(a.x); h[1] = __float2bfloat16(a.y);
        h[2] = __float2bfloat16(a.z); h[3] = __float2bfloat16(a.w);
        h[4] = __float2bfloat16(b.x); h[5] = __float2bfloat16(b.y);
        h[6] = __float2bfloat16(b.z); h[7] = __float2bfloat16(b.w);
        *(bf16x8*)&Pp[idx] = *(bf16x8*)h;
    } else if (bid < 544) {
        const int b  = bid - 512;
        const int k0 = (b & 3) * 64;
        const int h0 = ((b >> 2) & 3) * 64;
        const int z  = b >> 4;
        const float* W = z ? Wo : Ws;
        #pragma unroll
        for (int q = 0; q < 4; ++q) {
            int r = (t >> 4) + q * 16;
            int c = (t & 15) * 4;
            float4 f = *(const float4*)&W[(size_t)(k0 + r) * H_DIM + h0 + c];
            shbuf[r * 65 + c] = f.x; shbuf[r * 65 + c + 1] = f.y;
            shbuf[r * 65 + c + 2] = f.z; shbuf[r * 65 + c + 3] = f.w;
        }
        __syncthreads();
        #pragma unroll
        for (int q = 0; q < 2; ++q) {
            int idx = t + q * 256;
            int h   = idx >> 3;
            int kc  = idx & 7;
            __hip_bfloat16 u[8];
            #pragma unroll
            for (int j = 0; j < 8; ++j)
                u[j] = __float2bfloat16(shbuf[(kc * 8 + j) * 65 + h]);
            *(bf16x8*)&Wt[((size_t)z * H_DIM + h0 + h) * H_DIM + k0 + kc * 8] = *(bf16x8*)u;
        }
    } else if (bid < 608) {
        const int b  = bid - 544;
        const int i0 = b * 64;
        for (int idx = t; idx < 64 * C_DIM; idx += 256)
            shbuf[idx] = D[(size_t)i0 * C_DIM + idx];
        __syncthreads();
        const float wps = wsc[768];
        for (int o = t; o < 64 * (KT / 8); o += 256) {
            int r = o / (KT / 8), ch = o % (KT / 8);
            __hip_bfloat16 u[8];
            #pragma unroll
            for (int j = 0; j < 8; ++j) {
                int k = ch * 8 + j;
                u[j] = __float2bfloat16(k < C_DIM ? shbuf[r * C_DIM + k] : 0.f);
            }
            *(bf16x8*)&Dpack[(size_t)(i0 + r) * KT + ch * 8] = *(bf16x8*)u;
        }
        for (int o = t; o < 64 * 24; o += 256) {
            int r = o / 24, ch = o % 24;
            __hip_bfloat16 u[8];
            #pragma unroll
            for (int j = 0; j < 8; ++j) {
                int c = ch * 8 + j;
                u[j] = __float2bfloat16(c < C_DIM ? wps * shbuf[r * C_DIM + c] : 0.f);
            }
            *(bf16x8*)&Apack[(size_t)(i0 + r) * KP + H_DIM + ch * 8] = *(bf16x8*)u;
        }
    } else {
        const int q  = bid - 608;
        const int a0 = (q % 3) * 64;
        const int c0 = (q / 3) * 64;
        for (int o = t; o < 64 * 64; o += 256) {
            int r = o >> 6, c = o & 63;
            float v = 0.f;
            if (a0 + r < C_DIM && c0 + c < C_DIM)
                v = co[(size_t)(a0 + r) * C_DIM + c0 + c];
            shbuf[r * 65 + c] = v;
        }
        __syncthreads();
        const int nch = (a0 == 128) ? 4 : 8;
        for (int o = t; o < 64 * 8; o += 256) {
            int cl = o >> 3, ch = o & 7;
            if (ch < nch) {
                __hip_bfloat16 u[8];
                #pragma unroll
                for (int j = 0; j < 8; ++j)
                    u[j] = __float2bfloat16(shbuf[(ch * 8 + j) * 65 + cl]);
                *(bf16x8*)&coT[(size_t)(c0 + cl) * KT + a0 + ch * 8] = *(bf16x8*)u;
            }
        }
    }
}

// Merged producer kernel:
//  bid < 256 : sub/obj MFMA (tile 128x64, 4 waves, full-K single stage)
//  bid >= 256: tail MFMA  M = D @ co (64x64 tiles, frags direct from global)
__global__ __launch_bounds__(256) void k_mid(
    const ushort_t* __restrict__ Pp, const ushort_t* __restrict__ Wt,
    const ushort_t* __restrict__ Dpack, const ushort_t* __restrict__ coT,
    const float* __restrict__ bsub, const float* __restrict__ bobj,
    const float* __restrict__ wsc,
    __hip_bfloat16* __restrict__ Apack, __hip_bfloat16* __restrict__ Bpack,
    float* __restrict__ part, float* __restrict__ spart) {
    __shared__ ushort_t As[128 * 256];  // 64 KB
    __shared__ ushort_t Bs[64 * 256];   // 32 KB

    const int t = threadIdx.x;
    const int w = t >> 6, l = t & 63;
    const int wr = w >> 1, wc = w & 1;
    const int lr = l & 15, g = l >> 4;
    const int bid = blockIdx.x;

    if (bid < 256) {
        const int hblk = bid & 3;
        const int i0   = ((bid >> 2) & 31) * 128;
        const int z    = bid >> 7;
        const int j0   = hblk * 64;
        const float* bias = z ? bobj : bsub;
        const ushort_t* Wz = Wt + (size_t)z * H_DIM * H_DIM;

        #pragma unroll
        for (int r_ = 0; r_ < 16; ++r_) {
            int idx = t + r_ * 256, row = idx >> 5, cl = idx & 31;
            int cs = cl ^ (row & 7);
            GLL(Pp + (size_t)(i0 + row) * H_DIM + cs * 8, &As[idx * 8]);
        }
        #pragma unroll
        for (int r_ = 0; r_ < 8; ++r_) {
            int idx = t + r_ * 256, row = idx >> 5, cl = idx & 31;
            int cs = cl ^ (row & 7);
            GLL(Wz + (size_t)(j0 + row) * H_DIM + cs * 8, &Bs[idx * 8]);
        }
        __syncthreads();

        f32x4 acc[4][2];
        #pragma unroll
        for (int m = 0; m < 4; ++m)
            #pragma unroll
            for (int n = 0; n < 2; ++n) acc[m][n] = f32x4{0.f, 0.f, 0.f, 0.f};

        #pragma unroll
        for (int ks2 = 0; ks2 < 8; ++ks2) {
            bf16x8 a[4], b[2];
            int c = ks2 * 4 + g;
            #pragma unroll
            for (int m = 0; m < 4; ++m) {
                int Rl = wr * 64 + m * 16 + lr;
                int cl = c ^ (Rl & 7);
                a[m] = *(const bf16x8*)&As[(Rl * 32 + cl) * 8];
            }
            #pragma unroll
            for (int n = 0; n < 2; ++n) {
                int Rl = wc * 32 + n * 16 + lr;
                int cl = c ^ (Rl & 7);
                b[n] = *(const bf16x8*)&Bs[(Rl * 32 + cl) * 8];
            }
            #pragma unroll
            for (int m = 0; m < 4; ++m)
                #pragma unroll
                for (int n = 0; n < 2; ++n)
                    acc[m][n] = __builtin_amdgcn_mfma_f32_16x16x32_bf16(
                        a[m], b[n], acc[m][n], 0, 0, 0);
        }

        int hn[2]; float bb[2], wse[2], wmu[2];
        #pragma unroll
        for (int n = 0; n < 2; ++n) {
            hn[n]  = j0 + wc * 32 + n * 16 + lr;
            bb[n]  = bias[hn[n]];
            wse[n] = wsc[(z ? 512 : 256) + hn[n]];
            wmu[n] = wsc[hn[n]];
        }
        float* partq = part + (size_t)(z * 8 + hblk * 2 + wc) * N_DIM;
        #pragma unroll
        for (int m = 0; m < 4; ++m) {
            float p[4] = {0.f, 0.f, 0.f, 0.f};
            #pragma unroll
            for (int n = 0; n < 2; ++n)
                #pragma unroll
                for (int r = 0; r < 4; ++r) {
                    float v = acc[m][n][r] + bb[n];
                    v = v > 0.f ? v : 0.f;
                    int i = i0 + wr * 64 + m * 16 + g * 4 + r;
                    if (z) Apack[(size_t)i * KP + hn[n]] = __float2bfloat16(v * wmu[n]);
                    else   Bpack[(size_t)i * KP + hn[n]] = __float2bfloat16(v);
                    p[r] += v * wse[n];
                }
            #pragma unroll
            for (int r = 0; r < 4; ++r) {
                p[r] += __shfl_xor(p[r], 1);
                p[r] += __shfl_xor(p[r], 2);
                p[r] += __shfl_xor(p[r], 4);
                p[r] += __shfl_xor(p[r], 8);
            }
            if (lr == 0)
                #pragma unroll
                for (int r = 0; r < 4; ++r)
                    partq[i0 + wr * 64 + m * 16 + g * 4 + r] = p[r];
        }
    } else {
        const int q  = bid - 256;
        const int j0 = (q % 3) * 64;
        const int i0 = (q / 3) * 64;

        bf16x8 a[2][5], b[2][5];
        #pragma unroll
        for (int m = 0; m < 2; ++m) {
            const ushort_t* ap = Dpack + (size_t)(i0 + wr * 32 + m * 16 + lr) * KT + g * 8;
            #pragma unroll
            for (int ks = 0; ks < 5; ++ks) a[m][ks] = *(const bf16x8*)(ap + ks * 32);
        }
        #pragma unroll
        for (int n = 0; n < 2; ++n) {
            const ushort_t* bp = coT + (size_t)(j0 + wc * 32 + n * 16 + lr) * KT + g * 8;
            #pragma unroll
            for (int ks = 0; ks < 5; ++ks) b[n][ks] = *(const bf16x8*)(bp + ks * 32);
        }

        f32x4 acc[2][2];
        #pragma unroll
        for (int m = 0; m < 2; ++m)
            #pragma unroll
            for (int n = 0; n < 2; ++n) acc[m][n] = f32x4{0.f, 0.f, 0.f, 0.f};
        #pragma unroll
        for (int ks = 0; ks < 5; ++ks)
            #pragma unroll
            for (int m = 0; m < 2; ++m)
                #pragma unroll
                for (int n = 0; n < 2; ++n)
                    acc[m][n] = __builtin_amdgcn_mfma_f32_16x16x32_bf16(
                        a[m][ks], b[n][ks], acc[m][n], 0, 0, 0);

        float* sp = spart + (size_t)((q % 3) * 2 + wc) * N_DIM;
        #pragma unroll
        for (int m = 0; m < 2; ++m) {
            float p[4] = {0.f, 0.f, 0.f, 0.f};
            #pragma unroll
            for (int n = 0; n < 2; ++n) {
                int col = j0 + wc * 32 + n * 16 + lr;
                #pragma unroll
                for (int r = 0; r < 4; ++r) {
                    int i = i0 + wr * 32 + m * 16 + g * 4 + r;
                    float v = acc[m][n][r];
                    Bpack[(size_t)i * KP + H_DIM + col] = __float2bfloat16(v);
                    p[r] += v;
                }
            }
            #pragma unroll
            for (int r = 0; r < 4; ++r) {
                p[r] += __shfl_xor(p[r], 1);
                p[r] += __shfl_xor(p[r], 2);
                p[r] += __shfl_xor(p[r], 4);
                p[r] += __shfl_xor(p[r], 8);
            }
            if (lr == 0)
                #pragma unroll
                for (int r = 0; r < 4; ++r)
                    sp[i0 + wr * 32 + m * 16 + g * 4 + r] = p[r];
        }
    }
}

// Main: 256x256 tile, 8 waves (2M x 4N), BK=64, 2-phase dbuf with COUNTED
// vmcnt (T4) — prefetch stays in flight across raw s_barrier. Epilogue uses
// raw barriers (no vmcnt drain) so the store burst pipelines across m-chunks.
__global__ __launch_bounds__(512, 2) void k_main(
    const ushort_t* __restrict__ Apack, const ushort_t* __restrict__ Bpack,
    const float* __restrict__ part, const float* __restrict__ spart,
    const float* __restrict__ wsc, const float* __restrict__ bsc,
    float* __restrict__ out) {
    __shared__ ushort_t pool[2][2][256 * 64];   // 128 KB
    __shared__ float rbS[256], cbS[256];

    const int t = threadIdx.x;
    const int w = t >> 6, l = t & 63;
    const int wm = w >> 2, wn = w & 3;
    const int lr = l & 15, g = l >> 4;
    const int bid = blockIdx.x;
    const int swz = (bid & 7) * 32 + (bid >> 3);
    const int i0 = (swz >> 4) * 256;
    const int j0 = (swz & 15) * 256;

#define K_STAGE(buf, ks) do {                                                   \
    _Pragma("unroll")                                                           \
    for (int r_ = 0; r_ < 4; ++r_) {                                            \
        int idx_ = t + r_ * 512, row_ = idx_ >> 3, cl_ = idx_ & 7;              \
        int cs_ = cl_ ^ (row_ & 7);                                             \
        GLL(Apack + (size_t)(i0+row_)*KP + (ks)*64 + cs_*8, &pool[buf][0][idx_*8]); \
        GLL(Bpack + (size_t)(j0+row_)*KP + (ks)*64 + cs_*8, &pool[buf][1][idx_*8]); \
    }                                                                           \
} while (0)

#define K_COMPUTE(cur) do {                                                     \
    _Pragma("unroll")                                                           \
    for (int ks2 = 0; ks2 < 2; ++ks2) {                                         \
        bf16x8 a[8], b[4];                                                      \
        int c = ks2 * 4 + g;                                                    \
        _Pragma("unroll")                                                       \
        for (int m = 0; m < 8; ++m) {                                           \
            int Rl = wm * 128 + m * 16 + lr;                                    \
            int cl = c ^ (Rl & 7);                                              \
            a[m] = *(const bf16x8*)&pool[cur][0][(Rl * 8 + cl) * 8];            \
        }                                                                       \
        _Pragma("unroll")                                                       \
        for (int n = 0; n < 4; ++n) {                                           \
            int Rl = wn * 64 + n * 16 + lr;                                     \
            int cl = c ^ (Rl & 7);                                              \
            b[n] = *(const bf16x8*)&pool[cur][1][(Rl * 8 + cl) * 8];            \
        }                                                                       \
        _Pragma("unroll")                                                       \
        for (int m = 0; m < 8; ++m)                                             \
            _Pragma("unroll")                                                   \
            for (int n = 0; n < 4; ++n)                                         \
                acc[m][n] = __builtin_amdgcn_mfma_f32_16x16x32_bf16(            \
                    a[m], b[n], acc[m][n], 0, 0, 0);                            \
    }                                                                           \
} while (0)

    K_STAGE(0, 0);
    // fused bias computation (overlaps stage-0 latency)
    if (t < 256) {
        int i = i0 + t; float r = 0.f, si = 0.f;
        #pragma unroll
        for (int q = 8; q < 16; ++q) r += part[(size_t)q * N_DIM + i];
        #pragma unroll
        for (int q = 0; q < 6; ++q) si += spart[(size_t)q * N_DIM + i];
        rbS[t] = r + wsc[770] * si;
    } else {
        int j = j0 + (t - 256); float c = 0.f, sj = 0.f;
        #pragma unroll
        for (int q = 0; q < 8; ++q) c += part[(size_t)q * N_DIM + j];
        #pragma unroll
        for (int q = 0; q < 6; ++q) sj += spart[(size_t)q * N_DIM + j];
        cbS[t - 256] = c + wsc[769] * sj + bsc[0];
    }
    __syncthreads();   // one full drain: stage-0 + bias loads

    f32x4 acc[8][4];
    #pragma unroll
    for (int m = 0; m < 8; ++m)
        #pragma unroll
        for (int n = 0; n < 4; ++n) acc[m][n] = f32x4{0.f, 0.f, 0.f, 0.f};

    for (int ks = 0; ks < 6; ++ks) {
        const int cur = ks & 1;
        K_STAGE(cur ^ 1, ks + 1);                       // 8 GLL in flight
        asm volatile("s_waitcnt vmcnt(8)" ::: "memory"); // cur's loads done
        __builtin_amdgcn_s_barrier();
        __builtin_amdgcn_sched_barrier(0);
        K_COMPUTE(cur);
        __builtin_amdgcn_s_barrier();                   // reads done -> safe overwrite
        __builtin_amdgcn_sched_barrier(0);
    }
    asm volatile("s_waitcnt vmcnt(0)" ::: "memory");
    __builtin_amdgcn_s_barrier();
    __builtin_amdgcn_sched_barrier(0);
    K_COMPUTE(0);                                        // ks=6 -> buf 0
    __builtin_amdgcn_s_barrier();                       // all reads done before OutS reuse
    __builtin_amdgcn_sched_barrier(0);
#undef K_STAGE
#undef K_COMPUTE

    // Epilogue: sigmoid -> LDS bounce -> float4 stores; raw barriers keep
    // global stores in flight across m-chunks (no vmcnt drain).
    float cbv[4];
    #pragma unroll
    for (int n = 0; n < 4; ++n) cbv[n] = cbS[wn * 64 + n * 16 + lr];
    float* OutS = (float*)pool;   // [32][260] f32 = 33.3 KB
    #pragma unroll
    for (int m = 0; m < 8; ++m) {
        #pragma unroll
        for (int n = 0; n < 4; ++n) {
            #pragma unroll
            for (int r = 0; r < 4; ++r) {
                float rb = rbS[wm * 128 + m * 16 + g * 4 + r];
                float v  = acc[m][n][r] + rb + cbv[n];
                float e  = __expf(-v);
                OutS[(wm * 16 + g * 4 + r) * 260 + wn * 64 + n * 16 + lr] =
                    __builtin_amdgcn_rcpf(1.0f + e);
            }
        }
        asm volatile("s_waitcnt lgkmcnt(0)" ::: "memory");
        __builtin_amdgcn_s_barrier();
        __builtin_amdgcn_sched_barrier(0);
        {
            int rl = t >> 4, c16 = t & 15;
            int gr = i0 + (rl >> 4) * 128 + m * 16 + (rl & 15);
            float* op = out + (size_t)gr * N_DIM + j0;
            const float* rp = OutS + rl * 260;
            #pragma unroll
            for (int k = 0; k < 4; ++k) {
                float4 v4 = *(const float4*)(rp + (c16 + 16 * k) * 4);
                *(float4*)(op + (c16 + 16 * k) * 4) = v4;
            }
        }
        __builtin_amdgcn_s_barrier();   // ds_reads consumed by stores; safe to overwrite
        __builtin_amdgcn_sched_barrier(0);
    }
}

extern "C" void kernel_launch(void* const* d_in, const int* in_sizes, int n_in,
                              void* d_out, int out_size, void* d_ws, size_t ws_size,
                              hipStream_t stream) {
    const float* prepro = (const float*)d_in[0];
    const float* D      = (const float*)d_in[1];
    const float* co     = (const float*)d_in[2];
    const float* Wsub   = (const float*)d_in[3];
    const float* bsub   = (const float*)d_in[4];
    const float* Wobj   = (const float*)d_in[5];
    const float* bobj   = (const float*)d_in[6];
    const float* wsc    = (const float*)d_in[7];
    const float* bsc    = (const float*)d_in[8];
    float* out = (float*)d_out;

    char* ws = (char*)d_ws;
    __hip_bfloat16* Ppack = (__hip_bfloat16*)(ws + WSB_PPACK);
    __hip_bfloat16* Wt    = (__hip_bfloat16*)(ws + WSB_WT);
    __hip_bfloat16* Dpack = (__hip_bfloat16*)(ws + WSB_DPACK);
    __hip_bfloat16* coT   = (__hip_bfloat16*)(ws + WSB_COT);
    float* part  = (float*)(ws + WSB_PART);
    float* spart = (float*)(ws + WSB_SPART);
    __hip_bfloat16* Apack = (__hip_bfloat16*)(ws + WSB_APACK);
    __hip_bfloat16* Bpack = (__hip_bfloat16*)(ws + WSB_BPACK);

    k_cvt<<<617, 256, 0, stream>>>(prepro, Wsub, Wobj, D, co, wsc,
                                   Ppack, Wt, Dpack, coT, Apack);
    k_mid<<<448, 256, 0, stream>>>(
        (const ushort_t*)Ppack, (const ushort_t*)Wt,
        (const ushort_t*)Dpack, (const ushort_t*)coT,
        bsub, bobj, wsc, Apack, Bpack, part, spart);
    k_main<<<256, 512, 0, stream>>>(
        (const ushort_t*)Apack, (const ushort_t*)Bpack, part, spart, wsc, bsc, out);
}